// Round 14
// baseline (22.274 us; speedup 1.0000x reference)
//
#include <hip/hip_runtime.h>

#define K_TOTAL 32768
#define R_TOTAL 128
#define A_DIM   16
#define KW      16     // k-points per wave
#define KB      32     // k-points per block (2 chunks x 16)

// Rules-in-lanes, sparsity-aware:
//   Block = 256 thr = 4 waves = {2 k-chunks} x {2 rule-halves}.
//   Lane l of half h holds rule h*64+l; its folded FMA-form constants
//   (81 floats) live in VGPRs for the whole kernel -> ZERO per-rule
//   operand delivery (no LDS broadcasts, no SMEM records).
//   Per k: x[16] is wave-uniform -> s_load into SGPRs; inner op is
//   v_fma(sgpr, vgpr, vgpr): 5 VALU/dim + 1 fma/dim for z.
//   Early-outs over the wave's 64 rules x this k:
//     P(all 64 rules dead after 8 dims)  ~ 0.33 -> skip dims 8-15
//     P(all dead after 12 dims)          ~ 0.87 -> skip dims 12-15
//     P(all dead after 16 dims)          ~ 0.98 -> skip z-dot AND the
//       whole 12-op cross-lane reduction (runs for ~2% of k's only).
//   Final: 2 rule-halves merged through 512 B of LDS, coalesced store.
__global__ __launch_bounds__(256, 4)
void fuzzy_rl(const float* __restrict__ input,
              const float* __restrict__ abcd,
              const float* __restrict__ rho,
              float* __restrict__ out) {
    const int t     = threadIdx.x;
    const int lane  = t & 63;
    const int wv    = t >> 6;              // 0..3
    const int chunk = wv >> 1;             // k-chunk within block
    const int half  = wv & 1;              // rule half
    const int r     = half * 64 + lane;    // this lane's rule
    const int kbase = blockIdx.x * KB + chunk * KW;

    // ---- one-time: sort abcd and fold constants for this lane's rule ----
    float C0[A_DIM], C1[A_DIM], C2[A_DIM], C3[A_DIM], RH[A_DIM], BI;
    {
        const float4* ab = (const float4*)abcd + r * A_DIM;
        #pragma unroll
        for (int a = 0; a < A_DIM; ++a) {
            float4 v = ab[a];
            float v0 = v.x, v1 = v.y, v2 = v.z, v3 = v.w, s;
            s = fminf(v0, v1); v1 = fmaxf(v0, v1); v0 = s;
            s = fminf(v2, v3); v3 = fmaxf(v2, v3); v2 = s;
            s = fminf(v0, v2); v2 = fmaxf(v0, v2); v0 = s;
            s = fminf(v1, v3); v3 = fmaxf(v1, v3); v1 = s;
            s = fminf(v1, v2); v2 = fmaxf(v1, v2); v1 = s;
            // v0<=v1<=v2<=v3
            float iba = __builtin_amdgcn_rcpf(v1 - v0);
            float idc = __builtin_amdgcn_rcpf(v3 - v2);
            C0[a] =  iba;
            C1[a] = -v0 * iba;
            C2[a] = -idc;
            C3[a] =  v3 * idc;
        }
        const float* rr = rho + r * (A_DIM + 1);
        #pragma unroll
        for (int a = 0; a < A_DIM; ++a) RH[a] = rr[a];
        BI = rr[A_DIM];
    }

    float resn = 0.0f, resd = 0.0f;

    #pragma unroll
    for (int j = 0; j < KW; ++j) {
        // wave-uniform address -> scalar loads; x lives in SGPRs
        const float4* xp = (const float4*)(input + (size_t)(kbase + j) * A_DIM);
        float4 X0 = xp[0], X1 = xp[1], X2 = xp[2], X3 = xp[3];
        float sx[A_DIM] = { X0.x, X0.y, X0.z, X0.w,  X1.x, X1.y, X1.z, X1.w,
                            X2.x, X2.y, X2.z, X2.w,  X3.x, X3.y, X3.z, X3.w };

        float w = 1.0f;
        #pragma unroll
        for (int a = 0; a < 8; ++a) {
            float rise = fmaf(sx[a], C0[a], C1[a]);
            float fall = fmaf(sx[a], C2[a], C3[a]);
            w *= __builtin_amdgcn_fmed3f(fminf(rise, fall), 0.0f, 1.0f);
        }
        if (!__any(w != 0.0f)) continue;               // ~33% of k's stop here
        #pragma unroll
        for (int a = 8; a < 12; ++a) {
            float rise = fmaf(sx[a], C0[a], C1[a]);
            float fall = fmaf(sx[a], C2[a], C3[a]);
            w *= __builtin_amdgcn_fmed3f(fminf(rise, fall), 0.0f, 1.0f);
        }
        if (!__any(w != 0.0f)) continue;               // cum ~87%
        #pragma unroll
        for (int a = 12; a < 16; ++a) {
            float rise = fmaf(sx[a], C0[a], C1[a]);
            float fall = fmaf(sx[a], C2[a], C3[a]);
            w *= __builtin_amdgcn_fmed3f(fminf(rise, fall), 0.0f, 1.0f);
        }
        if (!__any(w != 0.0f)) continue;               // cum ~98%

        // ~2% of k's reach here: z-dot + cross-lane reduction
        float z = BI;
        #pragma unroll
        for (int a = 0; a < A_DIM; ++a) z = fmaf(sx[a], RH[a], z);

        float nm = z * w;
        float dn = w;
        #pragma unroll
        for (int s = 1; s < 64; s <<= 1) {
            nm += __shfl_xor(nm, s, 64);
            dn += __shfl_xor(dn, s, 64);
        }
        bool sel = (lane == j);
        resn = sel ? nm : resn;     // lane j keeps k = kbase + j
        resd = sel ? dn : resd;
    }

    // ---- merge the two rule-halves through LDS ----
    __shared__ float red[2][2][KW][2];                 // 512 B
    if (lane < KW) {
        red[chunk][half][lane][0] = resn;
        red[chunk][half][lane][1] = resd;
    }
    __syncthreads();

    if (t < KB) {
        int c = t >> 4, j = t & 15;
        float n = red[c][0][j][0] + red[c][1][j][0];
        float d = red[c][0][j][1] + red[c][1][j][1] + 1e-13f;
        out[blockIdx.x * KB + t] = n * __builtin_amdgcn_rcpf(d);
    }
}

// ---------------------------------------------------------------------------
extern "C" void kernel_launch(void* const* d_in, const int* in_sizes, int n_in,
                              void* d_out, int out_size, void* d_ws, size_t ws_size,
                              hipStream_t stream) {
    const float* input = (const float*)d_in[0];   // (K, A)    fp32
    const float* abcd  = (const float*)d_in[1];   // (R, A, 4) fp32
    const float* rho   = (const float*)d_in[2];   // (R, A+1)  fp32
    float* out = (float*)d_out;                   // (K,)      fp32

    fuzzy_rl<<<K_TOTAL / KB, 256, 0, stream>>>(input, abcd, rho, out);
}

// Round 15
// 16.863 us; speedup vs baseline: 1.3209x; 1.3209x over previous
//
#include <hip/hip_runtime.h>

#define K_TOTAL 32768
#define R_TOTAL 128
#define A_DIM   16
#define KB      128      // k-points per block (2 per lane)
#define RPW     8        // rules per wave (16 waves x 8 = 128)

#define REC 84   // floats per rule record in LDS (336 B = 21*16 -> f4-aligned)
// per-rule LDS record layout (floats), pair p = dims {2p, 2p+1}:
//   [ 4p .. 4p+3 ]      Q0[p] = { IBA0, IBA1, C1_0, C1_1 }   (p = 0..7)
//   [32+4p .. 32+4p+3]  Q1[p] = { NID0, NID1, C3_0, C3_1 }
//   [64..79]            rho[0..15]
//   [80]                bias ; [81..83] pad

typedef float v2f __attribute__((ext_vector_type(2)));

__device__ __forceinline__ float clamp01(float v) {
    return __builtin_amdgcn_fmed3f(v, 0.0f, 1.0f);
}

// one dim-pair, two k-instances; 2x ds_read_b128 delivers all 8 constants
__device__ __forceinline__ void memb_pair2(const float* rec, int p,
                                           const v2f* Xa, const v2f* Xb,
                                           v2f& Wa, v2f& Wb) {
    float4 q0 = *(const float4*)(rec + 4 * p);        // ds_read_b128
    float4 q1 = *(const float4*)(rec + 32 + 4 * p);   // ds_read_b128
    v2f iba = (v2f){q0.x, q0.y}, c1 = (v2f){q0.z, q0.w};
    v2f nid = (v2f){q1.x, q1.y}, c3 = (v2f){q1.z, q1.w};
    v2f ra = Xa[p] * iba + c1;    // v_pk_fma_f32
    v2f fa = Xa[p] * nid + c3;
    v2f rb = Xb[p] * iba + c1;
    v2f fb = Xb[p] * nid + c3;
    v2f Ma, Mb;
    Ma.x = clamp01(fminf(ra.x, fa.x));
    Ma.y = clamp01(fminf(ra.y, fa.y));
    Mb.x = clamp01(fminf(rb.x, fb.x));
    Mb.y = clamp01(fminf(rb.y, fb.y));
    Wa *= Ma;
    Wb *= Mb;
}

// Single fused kernel. 256 blocks x 1024 threads (16 waves, 1 block/CU).
// Block owns 128 k's: lane carries k = kbase+lane and kbase+64+lane.
// Wave wv folds ONLY its own 8 rules into its own LDS region (2 KB
// contiguous global reads), then proceeds with a wave-local lgkmcnt fence
// -- no block barrier between fold and compute. Phase 2: wave-uniform
// b128 LDS broadcasts feed packed-fp32 VALU for both k-instances;
// early-outs after dims 8/12/16 skip work whose contribution is exact +0.
__global__ __launch_bounds__(1024, 4)
void fuzzy_fused(const float* __restrict__ input,
                 const float* __restrict__ abcd,
                 const float* __restrict__ rho,
                 float* __restrict__ out) {
    __shared__ __align__(16) float tab[R_TOTAL * REC];   // 43008 B
    __shared__ float nsh[16][KB];                        // 8192 B
    __shared__ float dsh[16][KB];                        // 8192 B

    const int t     = threadIdx.x;
    const int lane  = t & 63;
    const int wv    = __builtin_amdgcn_readfirstlane(t >> 6);
    const int kbase = blockIdx.x * KB;
    float* wtab = tab + wv * RPW * REC;

    // -------- per-wave fold: 8 rules x 16 dims = 128 entries, 2/lane -------
    #pragma unroll
    for (int i = 0; i < 2; ++i) {
        int e  = lane + 64 * i;                // 0..127 within this wave
        int rr = e >> 4, a = e & 15, p = a >> 1, sl = a & 1;
        float4 v = ((const float4*)abcd)[wv * 128 + e];
        float v0 = v.x, v1 = v.y, v2 = v.z, v3 = v.w, s;
        s = fminf(v0, v1); v1 = fmaxf(v0, v1); v0 = s;
        s = fminf(v2, v3); v3 = fmaxf(v2, v3); v2 = s;
        s = fminf(v0, v2); v2 = fmaxf(v0, v2); v0 = s;
        s = fminf(v1, v3); v3 = fmaxf(v1, v3); v1 = s;
        s = fminf(v1, v2); v2 = fmaxf(v1, v2); v1 = s;
        // v0<=v1<=v2<=v3
        float iba = __builtin_amdgcn_rcpf(v1 - v0);
        float idc = __builtin_amdgcn_rcpf(v3 - v2);
        float* q = wtab + rr * REC;
        q[4 * p + sl]          =  iba;
        q[4 * p + 2 + sl]      = -v0 * iba;
        q[32 + 4 * p + sl]     = -idc;
        q[32 + 4 * p + 2 + sl] =  v3 * idc;
    }
    // rho for this wave's 8 rules: 8*17 = 136 floats, contiguous in global
    #pragma unroll
    for (int i = 0; i < 3; ++i) {
        int f = lane + 64 * i;
        if (f < RPW * (A_DIM + 1)) {
            int rr = f / (A_DIM + 1);
            int c  = f - rr * (A_DIM + 1);
            wtab[rr * REC + 64 + c] = rho[wv * RPW * (A_DIM + 1) + f];
        }
    }

    // per-lane coordinates for the two k-instances (overlap fold latency)
    v2f Xa[8], Xb[8];
    {
        const float4* xp = (const float4*)(input + (size_t)(kbase + lane) * A_DIM);
        float4 a0 = xp[0], a1 = xp[1], a2 = xp[2], a3 = xp[3];
        Xa[0] = (v2f){a0.x, a0.y}; Xa[1] = (v2f){a0.z, a0.w};
        Xa[2] = (v2f){a1.x, a1.y}; Xa[3] = (v2f){a1.z, a1.w};
        Xa[4] = (v2f){a2.x, a2.y}; Xa[5] = (v2f){a2.z, a2.w};
        Xa[6] = (v2f){a3.x, a3.y}; Xa[7] = (v2f){a3.z, a3.w};
        const float4* yp = (const float4*)(input + (size_t)(kbase + 64 + lane) * A_DIM);
        float4 b0 = yp[0], b1 = yp[1], b2 = yp[2], b3 = yp[3];
        Xb[0] = (v2f){b0.x, b0.y}; Xb[1] = (v2f){b0.z, b0.w};
        Xb[2] = (v2f){b1.x, b1.y}; Xb[3] = (v2f){b1.z, b1.w};
        Xb[4] = (v2f){b2.x, b2.y}; Xb[5] = (v2f){b2.z, b2.w};
        Xb[6] = (v2f){b3.x, b3.y}; Xb[7] = (v2f){b3.z, b3.w};
    }

    // wave-local fence: this wave's LDS writes complete before its reads.
    // (No cross-wave hazard: each wave reads only its own region.)
    asm volatile("s_waitcnt lgkmcnt(0)" ::: "memory");
    __builtin_amdgcn_sched_barrier(0);

    // -------- Phase 2: stream this wave's 8 rules --------------------------
    float numA = 0.0f, denA = 0.0f, numB = 0.0f, denB = 0.0f;

    #pragma unroll
    for (int rr = 0; rr < RPW; ++rr) {
        const float* rec = wtab + rr * REC;    // wave-uniform -> broadcasts

        v2f Wa = (v2f){1.0f, 1.0f}, Wb = (v2f){1.0f, 1.0f};
        memb_pair2(rec, 0, Xa, Xb, Wa, Wb);
        memb_pair2(rec, 1, Xa, Xb, Wa, Wb);
        memb_pair2(rec, 2, Xa, Xb, Wa, Wb);
        memb_pair2(rec, 3, Xa, Xb, Wa, Wb);
        float w8a = Wa.x * Wa.y, w8b = Wb.x * Wb.y;
        if (__any((w8a != 0.0f) | (w8b != 0.0f))) {          // skip p~0.11
            memb_pair2(rec, 4, Xa, Xb, Wa, Wb);
            memb_pair2(rec, 5, Xa, Xb, Wa, Wb);
            float w12a = Wa.x * Wa.y, w12b = Wb.x * Wb.y;
            if (__any((w12a != 0.0f) | (w12b != 0.0f))) {    // skip p~0.75
                memb_pair2(rec, 6, Xa, Xb, Wa, Wb);
                memb_pair2(rec, 7, Xa, Xb, Wa, Wb);
                float wfa = Wa.x * Wa.y, wfb = Wb.x * Wb.y;
                if (__any((wfa != 0.0f) | (wfb != 0.0f))) {  // skip p~0.96
                    v2f accA = (v2f){rec[80], 0.0f};         // bias
                    v2f accB = (v2f){rec[80], 0.0f};
                    #pragma unroll
                    for (int p4 = 0; p4 < 4; ++p4) {
                        float4 rh = *(const float4*)(rec + 64 + 4 * p4);
                        v2f r0 = (v2f){rh.x, rh.y}, r1 = (v2f){rh.z, rh.w};
                        accA += Xa[2*p4] * r0;  accA += Xa[2*p4+1] * r1;
                        accB += Xb[2*p4] * r0;  accB += Xb[2*p4+1] * r1;
                    }
                    float za = accA.x + accA.y;
                    float zb = accB.x + accB.y;
                    numA = fmaf(za, wfa, numA);  denA += wfa;
                    numB = fmaf(zb, wfb, numB);  denB += wfb;
                }
            }
        }
    }

    // -------- Phase 3: reduce across the 16 waves --------------------------
    nsh[wv][lane]      = numA;
    dsh[wv][lane]      = denA;
    nsh[wv][64 + lane] = numB;
    dsh[wv][64 + lane] = denB;
    __syncthreads();

    if (t < KB) {
        float n = 0.0f, d = 0.0f;
        #pragma unroll
        for (int c = 0; c < 16; ++c) { n += nsh[c][t]; d += dsh[c][t]; }
        out[kbase + t] = n * __builtin_amdgcn_rcpf(d + 1e-13f);
    }
}

// ---------------------------------------------------------------------------
extern "C" void kernel_launch(void* const* d_in, const int* in_sizes, int n_in,
                              void* d_out, int out_size, void* d_ws, size_t ws_size,
                              hipStream_t stream) {
    const float* input = (const float*)d_in[0];   // (K, A)    fp32
    const float* abcd  = (const float*)d_in[1];   // (R, A, 4) fp32
    const float* rho   = (const float*)d_in[2];   // (R, A+1)  fp32
    float* out = (float*)d_out;                   // (K,)      fp32

    fuzzy_fused<<<K_TOTAL / KB, 1024, 0, stream>>>(input, abcd, rho, out);
}